// Round 23
// baseline (106.478 us; speedup 1.0000x reference)
//
#include <hip/hip_runtime.h>
#include <hip/hip_bf16.h>
#include <math.h>

#define B_    4
#define T_    4096
#define E_    768
#define H_    6
#define D_    64
#define HD_   384
#define G_    1024
#define RATIO_ 4
#define TOPK_ 8
#define MT_   (B_*T_)   // 16384 rows total
#define NS_   1152      // stacked N: [384 q][768 kg-interleaved]

typedef __attribute__((ext_vector_type(8))) short short8;
typedef __attribute__((ext_vector_type(4))) float f32x4;
typedef __hip_bfloat16 bf16;

#define GLD16(g, l) __builtin_amdgcn_global_load_lds( \
    (const __attribute__((address_space(1))) void*)(g), \
    (__attribute__((address_space(3))) void*)(l), 16, 0, 0)

static __device__ __forceinline__ unsigned short f2bf(float f) {
  bf16 h = __float2bfloat16(f);
  return __builtin_bit_cast(unsigned short, h);
}
static __device__ __forceinline__ unsigned umax_(unsigned a, unsigned b) { return a > b ? a : b; }
static __device__ __forceinline__ unsigned umin_(unsigned a, unsigned b) { return a > b ? b : a; }

// ---------------------------------------------------------------------------
// FUSED conversions: blocks [0,6144) convert x f32->bf16 (8 elems/thread);
// blocks [6144,7008) transpose+convert+stack weights into Ws [1152][768].
// ---------------------------------------------------------------------------
__global__ __launch_bounds__(256) void cvt_fused(
    const float* __restrict__ xin, const float* __restrict__ wq,
    const float* __restrict__ wk, const float* __restrict__ wg,
    bf16* __restrict__ xout, bf16* __restrict__ wsout)
{
  __shared__ float t[32][33];
  const int bid = blockIdx.x;
  if (bid < 6144) {
    size_t i = (size_t)bid * 256 + threadIdx.x;
    const float4* p = reinterpret_cast<const float4*>(xin) + i * 2;
    float4 v0 = p[0], v1 = p[1];
    float f[8] = {v0.x, v0.y, v0.z, v0.w, v1.x, v1.y, v1.z, v1.w};
    union { unsigned short u[8]; short8 v; } r;
#pragma unroll
    for (int k = 0; k < 8; ++k) r.u[k] = f2bf(f[k]);
    *reinterpret_cast<short8*>(xout + i * 8) = r.v;
    return;
  }
  const int wb = bid - 6144;          // 0..863
  const int z = wb / 288;             // 0..2
  const int rr = wb - z * 288;
  const int bx = rr % 24, by = rr / 24;
  const float* src = z == 0 ? wq : (z == 1 ? wk : wg);
  int r = threadIdx.x >> 5, c = threadIdx.x & 31;
  int k0 = bx * 32, n0 = by * 32;
#pragma unroll
  for (int i = 0; i < 4; ++i)
    t[r + i * 8][c] = src[(size_t)(k0 + r + i * 8) * HD_ + n0 + c];
  __syncthreads();
#pragma unroll
  for (int i = 0; i < 4; ++i) {
    int cc = n0 + r + i * 8;
    int ro = (z == 0) ? cc : 384 + ((cc >> 4) << 5) + ((z - 1) << 4) + (cc & 15);
    wsout[(size_t)ro * E_ + k0 + c] = __float2bfloat16(t[c][r + i * 8]);
  }
}

// ---------------------------------------------------------------------------
// Fused projection GEMM, BK=64 (proven 48.6us): [MT x 768] @ Ws^T ->
// q (rmsnormed) + keys (pooled+rmsnormed). 128x128 tile, 4 waves in M.
// ---------------------------------------------------------------------------
__global__ __launch_bounds__(256, 3) void gemm_qkg_mfma(
    const bf16* __restrict__ X, const bf16* __restrict__ Ws,
    const float* __restrict__ ape, bf16* __restrict__ Q,
    bf16* __restrict__ keys)
{
  __shared__ bf16 lds[2][8192];   // [128 rows][64 k] per buf = 16KB
  const int tid = threadIdx.x;
  const int lane = tid & 63, wv = tid >> 6;
  const int ll = lane & 15, lh = lane >> 4;
  const int m0 = blockIdx.x * 128, n0 = blockIdx.y * 128;
  const int srow = tid >> 3;
  const int sslot = (((tid & 7) ^ ((tid >> 3) & 7)) << 3);
  const bf16* pS = Ws + (size_t)(n0 + srow) * E_ + sslot;
  const bf16* pA0 = X + (size_t)(m0 + wv * 32 + ll) * E_ + lh * 8;
  const bf16* pA1 = pA0 + (size_t)16 * E_;

#define STAGE(b, k0) do { \
    char* base_ = (char*)&lds[b][0] + tid * 16; \
    GLD16(pS + (k0),            base_); \
    GLD16(pS + 32 * E_ + (k0),  base_ + 4096); \
    GLD16(pS + 64 * E_ + (k0),  base_ + 8192); \
    GLD16(pS + 96 * E_ + (k0),  base_ + 12288); \
  } while (0)
#define LOAD_A(dst, k0) do { \
    dst[0][0] = *reinterpret_cast<const short8*>(pA0 + (k0)); \
    dst[0][1] = *reinterpret_cast<const short8*>(pA0 + (k0) + 32); \
    dst[1][0] = *reinterpret_cast<const short8*>(pA1 + (k0)); \
    dst[1][1] = *reinterpret_cast<const short8*>(pA1 + (k0) + 32); \
  } while (0)

  f32x4 acc[2][8];
#pragma unroll
  for (int m = 0; m < 2; ++m)
#pragma unroll
    for (int n = 0; n < 8; ++n) acc[m][n] = (f32x4){0.f, 0.f, 0.f, 0.f};

  short8 curA[2][2], nxtA[2][2];   // [m][ks]
  LOAD_A(curA, 0);
  STAGE(0, 0);
#pragma unroll
  for (int m = 0; m < 2; ++m)
#pragma unroll
    for (int s = 0; s < 2; ++s) nxtA[m][s] = curA[m][s];

#pragma unroll
  for (int k = 0; k < 12; ++k) {
    const int k0 = k * 64;
    if (k < 11) {
      LOAD_A(nxtA, k0 + 64);
      STAGE((k + 1) & 1, k0 + 64);
    }
    if (k < 11) asm volatile("s_waitcnt vmcnt(8)" ::: "memory");
    else        asm volatile("s_waitcnt vmcnt(0)" ::: "memory");
    __builtin_amdgcn_s_barrier();
    __builtin_amdgcn_sched_barrier(0);
    const bf16* Lb = &lds[k & 1][0];
    short8 b0[8];
#pragma unroll
    for (int n = 0; n < 8; ++n)
      b0[n] = *reinterpret_cast<const short8*>(
          &Lb[(n * 16 + ll) * 64 + ((lh ^ (ll & 7)) << 3)]);
    asm volatile("s_waitcnt lgkmcnt(0)" ::: "memory");
    __builtin_amdgcn_sched_barrier(0);
#pragma unroll
    for (int m = 0; m < 2; ++m)
#pragma unroll
      for (int n = 0; n < 8; ++n)
        acc[m][n] = __builtin_amdgcn_mfma_f32_16x16x32_bf16(curA[m][0], b0[n], acc[m][n], 0, 0, 0);
    short8 b1[8];
#pragma unroll
    for (int n = 0; n < 8; ++n)
      b1[n] = *reinterpret_cast<const short8*>(
          &Lb[(n * 16 + ll) * 64 + (((4 + lh) ^ (ll & 7)) << 3)]);
    asm volatile("s_waitcnt lgkmcnt(0)" ::: "memory");
    __builtin_amdgcn_sched_barrier(0);
    __builtin_amdgcn_s_barrier();
#pragma unroll
    for (int m = 0; m < 2; ++m)
#pragma unroll
      for (int n = 0; n < 8; ++n)
        acc[m][n] = __builtin_amdgcn_mfma_f32_16x16x32_bf16(curA[m][1], b1[n], acc[m][n], 0, 0, 0);
#pragma unroll
    for (int m = 0; m < 2; ++m)
#pragma unroll
      for (int s = 0; s < 2; ++s) curA[m][s] = nxtA[m][s];
  }
#undef STAGE
#undef LOAD_A

  if (blockIdx.y < 3) {
#pragma unroll
    for (int m = 0; m < 2; ++m)
#pragma unroll
      for (int j = 0; j < 4; ++j) {
        int row = m0 + wv * 32 + m * 16 + lh * 4 + j;
#pragma unroll
        for (int h = 0; h < 2; ++h) {
          float ss = 0.f;
#pragma unroll
          for (int n = 4 * h; n < 4 * h + 4; ++n) ss += acc[m][n][j] * acc[m][n][j];
          ss += __shfl_xor(ss, 1, 64); ss += __shfl_xor(ss, 2, 64);
          ss += __shfl_xor(ss, 4, 64); ss += __shfl_xor(ss, 8, 64);
          float scl = rsqrtf(ss * (1.0f / D_) + 1e-6f);
#pragma unroll
          for (int n = 4 * h; n < 4 * h + 4; ++n)
            Q[(size_t)row * HD_ + n0 + n * 16 + ll] =
                __float2bfloat16(acc[m][n][j] * scl);
        }
      }
  } else {
    const int hcb = (n0 - 384) >> 1;
    float apev[4][4];
#pragma unroll
    for (int p = 0; p < 4; ++p) {
      int hc = hcb + p * 16 + ll;
#pragma unroll
      for (int j = 0; j < 4; ++j) apev[p][j] = ape[j * HD_ + hc];
    }
#pragma unroll
    for (int m = 0; m < 2; ++m) {
      float pooled[4];
#pragma unroll
      for (int p = 0; p < 4; ++p) {
        float g0 = acc[m][2 * p + 1][0] + apev[p][0];
        float g1 = acc[m][2 * p + 1][1] + apev[p][1];
        float g2 = acc[m][2 * p + 1][2] + apev[p][2];
        float g3 = acc[m][2 * p + 1][3] + apev[p][3];
        float mx = fmaxf(fmaxf(g0, g1), fmaxf(g2, g3));
        float e0 = expf(g0 - mx), e1 = expf(g1 - mx);
        float e2 = expf(g2 - mx), e3 = expf(g3 - mx);
        float inv = 1.0f / (e0 + e1 + e2 + e3);
        pooled[p] = (acc[m][2 * p][0] * e0 + acc[m][2 * p][1] * e1 +
                     acc[m][2 * p][2] * e2 + acc[m][2 * p][3] * e3) * inv;
      }
      float ss = pooled[0] * pooled[0] + pooled[1] * pooled[1] +
                 pooled[2] * pooled[2] + pooled[3] * pooled[3];
      ss += __shfl_xor(ss, 1, 64); ss += __shfl_xor(ss, 2, 64);
      ss += __shfl_xor(ss, 4, 64); ss += __shfl_xor(ss, 8, 64);
      float scl = rsqrtf(ss * (1.0f / D_) + 1e-6f);
      int prow = (m0 >> 2) + wv * 8 + m * 4 + lh;
#pragma unroll
      for (int p = 0; p < 4; ++p)
        keys[(size_t)prow * HD_ + hcb + p * 16 + ll] =
            __float2bfloat16(pooled[p] * scl);
    }
  }
}

#define CEx(a, bb) { unsigned h_ = umax_(a, bb), l_ = umin_(a, bb); a = h_; bb = l_; }
#define MERGE4() \
  _Pragma("unroll") \
  for (int st = 0; st < 2; ++st) { \
    const int off = 16 << st; \
    unsigned p0 = (unsigned)__shfl_xor((int)v0, off, 64); \
    unsigned p1 = (unsigned)__shfl_xor((int)v1, off, 64); \
    unsigned p2 = (unsigned)__shfl_xor((int)v2, off, 64); \
    unsigned p3 = (unsigned)__shfl_xor((int)v3, off, 64); \
    unsigned p4 = (unsigned)__shfl_xor((int)v4, off, 64); \
    unsigned p5 = (unsigned)__shfl_xor((int)v5, off, 64); \
    unsigned p6 = (unsigned)__shfl_xor((int)v6, off, 64); \
    unsigned p7 = (unsigned)__shfl_xor((int)v7, off, 64); \
    unsigned w0 = umax_(v0, p7), w1 = umax_(v1, p6); \
    unsigned w2 = umax_(v2, p5), w3 = umax_(v3, p4); \
    unsigned w4 = umax_(v4, p3), w5 = umax_(v5, p2); \
    unsigned w6 = umax_(v6, p1), w7 = umax_(v7, p0); \
    CEx(w0, w4); CEx(w1, w5); CEx(w2, w6); CEx(w3, w7); \
    CEx(w0, w2); CEx(w1, w3); CEx(w4, w6); CEx(w5, w7); \
    CEx(w0, w1); CEx(w2, w3); CEx(w4, w5); CEx(w6, w7); \
    v0 = w0; v1 = w1; v2 = w2; v3 = w3; v4 = w4; v5 = w5; v6 = w6; v7 = w7; \
  }

// ---------------------------------------------------------------------------
// Score + top-8 + in-kernel mask write. 4 waves/block (2x waves/SIMD of R19):
// wave pair p owns 16 t-rows; sub-wave (w&1) computes alternating key tiles;
// all 4 waves co-stage (6 GLD16/thread). Same staged bytes, same grid, 2x
// latency hiding, half the serial INS chain per wave. Final two-list merge
// via 1KB LDS. vmcnt: zero-fill(32/thread) + S(0)=6 retired by first
// vmcnt(6); every thread ends with vmcnt(0) -> __syncthreads -> scatter.
// ---------------------------------------------------------------------------
__global__ __launch_bounds__(256, 2) void score_topk8(
    const bf16* __restrict__ Qall, const bf16* __restrict__ Kall,
    int* __restrict__ mask, int* __restrict__ ends)
{
  __shared__ bf16 kbuf[2][12288];   // [32 g-rows][48 slots of 16B], swizzled
  __shared__ unsigned top2[2][16][8];
  const int x = blockIdx.x;         // 0..127
  const int b = blockIdx.y;
  const int s = (b < 2) ? x : 127 - x;   // complementary balance pairing
  const int R0 = s << 5;                 // 32 t-rows per block
  const int tid = threadIdx.x;
  const int w = tid >> 6;                // wave 0..3
  const int p = w >> 1;                  // row-pair: rows [R0+16p, R0+16p+16)
  const int sub = w & 1;                 // tile parity for this wave
  const int lane = tid & 63;
  const int ll = lane & 15, lh = lane >> 4;

  if (x == 0 && b == 0) {                // group_ends (once)
    int g = tid;
#pragma unroll
    for (int c = 0; c < 4; ++c, g += 256) {
      int e = (g << 2) + 3;
      ends[g] = e < T_ - 1 ? e : T_ - 1;
    }
  }

  // zero-fill this block's 32 mask rows (128KB); oldest vmcnt-queue entries.
  int* mbase = mask + ((size_t)b * T_ + R0) * G_;
  {
    int4* m4 = reinterpret_cast<int4*>(mbase);
    const int4 z = make_int4(0, 0, 0, 0);
#pragma unroll
    for (int i = 0; i < 32; ++i) m4[i * 256 + tid] = z;
  }

  const bf16* Qb = Qall + (size_t)b * T_ * HD_;
  const bf16* Kb = Kall + (size_t)b * G_ * HD_;
  const int t = R0 + 16 * p + ll;        // this lane's row
  const int gmax = (t + 1) >> 2;
  const int ntw = ((((R0 + 16 * p) >> 2) + 4) + 31) >> 5;  // pair's tiles
  const int nt  = ((((R0 + 16) >> 2) + 4) + 31) >> 5;      // block tiles

  // staging: 6 16B units/thread: u = i*256+tid -> g-row r=u/48, phys slot
  // sp=u%48, swizzled source slot sl=sp^(r&7)  (rule 21: linear dest).
  const bf16* ksrc[6];
  int sdst[6];
#pragma unroll
  for (int i = 0; i < 6; ++i) {
    int u = i * 256 + tid;
    int r = u / 48, sp = u - r * 48;
    int sl = sp ^ (r & 7);
    ksrc[i] = Kb + (size_t)r * HD_ + sl * 8;
    sdst[i] = u * 16;
  }
  // q frags (12 x 16B, once per kernel)
  short8 qf[12];
  {
    const bf16* pQ = Qb + (size_t)t * HD_ + lh * 8;
#pragma unroll
    for (int k = 0; k < 12; ++k)
      qf[k] = *reinterpret_cast<const short8*>(pQ + k * 32);
  }

#define KSTAGE(bf, g0) do { \
    char* bb_ = (char*)&kbuf[bf][0]; \
    _Pragma("unroll") \
    for (int i = 0; i < 6; ++i) \
      GLD16(ksrc[i] + (size_t)(g0) * HD_, bb_ + sdst[i]); \
  } while (0)

  unsigned v0 = 0, v1 = 0, v2 = 0, v3 = 0, v4 = 0, v5 = 0, v6 = 0, v7 = 0;
#define INS(xx) do { unsigned k_ = (xx), t_; \
    t_ = umax_(v0, k_); k_ = umin_(v0, k_); v0 = t_; \
    t_ = umax_(v1, k_); k_ = umin_(v1, k_); v1 = t_; \
    t_ = umax_(v2, k_); k_ = umin_(v2, k_); v2 = t_; \
    t_ = umax_(v3, k_); k_ = umin_(v3, k_); v3 = t_; \
    t_ = umax_(v4, k_); k_ = umin_(v4, k_); v4 = t_; \
    t_ = umax_(v5, k_); k_ = umin_(v5, k_); v5 = t_; \
    t_ = umax_(v6, k_); k_ = umin_(v6, k_); v6 = t_; \
    t_ = umax_(v7, k_); k_ = umin_(v7, k_); v7 = t_; } while (0)

  KSTAGE(0, 0);
  for (int mg = 0; mg < nt; ++mg) {
    if (mg + 1 < nt) {
      KSTAGE((mg + 1) & 1, (mg + 1) * 32);
      asm volatile("s_waitcnt vmcnt(6)" ::: "memory");
    } else {
      asm volatile("s_waitcnt vmcnt(0)" ::: "memory");
    }
    __builtin_amdgcn_s_barrier();          // buf[mg&1] staged by all waves
    __builtin_amdgcn_sched_barrier(0);
    if (mg < ntw && (mg & 1) == sub) {     // wave-uniform predicate
      const char* Lb = (const char*)&kbuf[mg & 1][0];
      f32x4 acc0 = (f32x4){0.f, 0.f, 0.f, 0.f};
      f32x4 acc1 = (f32x4){0.f, 0.f, 0.f, 0.f};
#pragma unroll
      for (int kk = 0; kk < 12; ++kk) {
        int sl = 4 * kk + lh;
        short8 k0 = *reinterpret_cast<const short8*>(
            Lb + (size_t)ll * 768 + ((sl ^ (ll & 7)) << 4));
        short8 k1 = *reinterpret_cast<const short8*>(
            Lb + (size_t)(16 + ll) * 768 + ((sl ^ (ll & 7)) << 4));
        acc0 = __builtin_amdgcn_mfma_f32_16x16x32_bf16(k0, qf[kk], acc0, 0, 0, 0);
        acc1 = __builtin_amdgcn_mfma_f32_16x16x32_bf16(k1, qf[kk], acc1, 0, 0, 0);
      }
      const int g0 = mg * 32;
      // |dot| < 384 (rmsnorm'd operands) -> dot+512 > 0: u32-order-isomorphic
#pragma unroll
      for (int j = 0; j < 4; ++j) {
        int g = g0 + lh * 4 + j;
        float xv = acc0[j] + 512.0f;
        unsigned key = (g < gmax)
            ? ((__builtin_bit_cast(unsigned, xv) & 0xFFFFFC00u) |
               (unsigned)(1023 - g))
            : 0u;
        INS(key);
      }
#pragma unroll
      for (int j = 0; j < 4; ++j) {
        int g = g0 + 16 + lh * 4 + j;
        float xv = acc1[j] + 512.0f;
        unsigned key = (g < gmax)
            ? ((__builtin_bit_cast(unsigned, xv) & 0xFFFFFC00u) |
               (unsigned)(1023 - g))
            : 0u;
        INS(key);
      }
    }
    __builtin_amdgcn_s_barrier();          // reads of buf[mg&1] done
  }
#undef INS
#undef KSTAGE

  MERGE4();                                // merge 4 lh-lanes within wave

  if (sub == 1 && lh == 0) {               // odd sub-wave -> LDS
    unsigned* tp = &top2[p][ll][0];
    tp[0] = v0; tp[1] = v1; tp[2] = v2; tp[3] = v3;
    tp[4] = v4; tp[5] = v5; tp[6] = v6; tp[7] = v7;
  }
  __syncthreads();   // all threads past vmcnt(0): zero-fill globally retired

  if (sub == 0 && lh == 0) {               // two-list merge + scatter
    const unsigned* tp = &top2[p][ll][0];
    unsigned u0 = tp[0], u1 = tp[1], u2 = tp[2], u3 = tp[3];
    unsigned u4 = tp[4], u5 = tp[5], u6 = tp[6], u7 = tp[7];
    unsigned w0 = umax_(v0, u7), w1 = umax_(v1, u6);
    unsigned w2 = umax_(v2, u5), w3 = umax_(v3, u4);
    unsigned w4 = umax_(v4, u3), w5 = umax_(v5, u2);
    unsigned w6 = umax_(v6, u1), w7 = umax_(v7, u0);
    CEx(w0, w4); CEx(w1, w5); CEx(w2, w6); CEx(w3, w7);
    CEx(w0, w2); CEx(w1, w3); CEx(w4, w6); CEx(w5, w7);
    CEx(w0, w1); CEx(w2, w3); CEx(w4, w5); CEx(w6, w7);
    int* rb = mbase + (size_t)(16 * p + ll) * G_;
    if (w0) rb[1023 - (w0 & 1023)] = 1;
    if (w1) rb[1023 - (w1 & 1023)] = 1;
    if (w2) rb[1023 - (w2 & 1023)] = 1;
    if (w3) rb[1023 - (w3 & 1023)] = 1;
    if (w4) rb[1023 - (w4 & 1023)] = 1;
    if (w5) rb[1023 - (w5 & 1023)] = 1;
    if (w6) rb[1023 - (w6 & 1023)] = 1;
    if (w7) rb[1023 - (w7 & 1023)] = 1;
  }
}

extern "C" void kernel_launch(void* const* d_in, const int* in_sizes, int n_in,
                              void* d_out, int out_size, void* d_ws, size_t ws_size,
                              hipStream_t stream)
{
  const float* x   = (const float*)d_in[0];
  const float* wq  = (const float*)d_in[1];
  const float* wk  = (const float*)d_in[2];
  const float* wg  = (const float*)d_in[3];
  const float* ape = (const float*)d_in[4];

  // ws: Ws[1152][768] bf16 | q[16384][384] bf16 | keys[4096][384] bf16
  bf16* Ws   = (bf16*)d_ws;
  bf16* qb   = Ws + (size_t)NS_ * E_;
  bf16* keys = qb + (size_t)MT_ * HD_;

  // x_bf16 staged in d_out (dead before the mask write overwrites it)
  bf16* xb = (bf16*)d_out;

  cvt_fused<<<dim3(6144 + 864), dim3(256), 0, stream>>>(x, wq, wk, wg, xb, Ws);

  gemm_qkg_mfma<<<dim3(MT_ / 128, NS_ / 128), dim3(256), 0, stream>>>(
      xb, Ws, ape, qb, keys);

  score_topk8<<<dim3(128, B_), dim3(256), 0, stream>>>(
      qb, keys, (int*)d_out, (int*)d_out + (size_t)B_ * T_ * G_);
}

// Round 24
// 103.798 us; speedup vs baseline: 1.0258x; 1.0258x over previous
//
#include <hip/hip_runtime.h>
#include <hip/hip_bf16.h>
#include <math.h>

#define B_    4
#define T_    4096
#define E_    768
#define H_    6
#define D_    64
#define HD_   384
#define G_    1024
#define RATIO_ 4
#define TOPK_ 8
#define MT_   (B_*T_)   // 16384 rows total
#define NS_   1152      // stacked N: [384 q][768 kg-interleaved]

typedef __attribute__((ext_vector_type(8))) short short8;
typedef __attribute__((ext_vector_type(4))) float f32x4;
typedef __hip_bfloat16 bf16;

#define GLD16(g, l) __builtin_amdgcn_global_load_lds( \
    (const __attribute__((address_space(1))) void*)(g), \
    (__attribute__((address_space(3))) void*)(l), 16, 0, 0)

static __device__ __forceinline__ unsigned short f2bf(float f) {
  bf16 h = __float2bfloat16(f);
  return __builtin_bit_cast(unsigned short, h);
}
static __device__ __forceinline__ unsigned umax_(unsigned a, unsigned b) { return a > b ? a : b; }
static __device__ __forceinline__ unsigned umin_(unsigned a, unsigned b) { return a > b ? b : a; }

// ---------------------------------------------------------------------------
// FUSED conversions: blocks [0,6144) convert x f32->bf16 (8 elems/thread);
// blocks [6144,7008) transpose+convert+stack weights into Ws [1152][768].
// ---------------------------------------------------------------------------
__global__ __launch_bounds__(256) void cvt_fused(
    const float* __restrict__ xin, const float* __restrict__ wq,
    const float* __restrict__ wk, const float* __restrict__ wg,
    bf16* __restrict__ xout, bf16* __restrict__ wsout)
{
  __shared__ float t[32][33];
  const int bid = blockIdx.x;
  if (bid < 6144) {
    size_t i = (size_t)bid * 256 + threadIdx.x;
    const float4* p = reinterpret_cast<const float4*>(xin) + i * 2;
    float4 v0 = p[0], v1 = p[1];
    float f[8] = {v0.x, v0.y, v0.z, v0.w, v1.x, v1.y, v1.z, v1.w};
    union { unsigned short u[8]; short8 v; } r;
#pragma unroll
    for (int k = 0; k < 8; ++k) r.u[k] = f2bf(f[k]);
    *reinterpret_cast<short8*>(xout + i * 8) = r.v;
    return;
  }
  const int wb = bid - 6144;          // 0..863
  const int z = wb / 288;             // 0..2
  const int rr = wb - z * 288;
  const int bx = rr % 24, by = rr / 24;
  const float* src = z == 0 ? wq : (z == 1 ? wk : wg);
  int r = threadIdx.x >> 5, c = threadIdx.x & 31;
  int k0 = bx * 32, n0 = by * 32;
#pragma unroll
  for (int i = 0; i < 4; ++i)
    t[r + i * 8][c] = src[(size_t)(k0 + r + i * 8) * HD_ + n0 + c];
  __syncthreads();
#pragma unroll
  for (int i = 0; i < 4; ++i) {
    int cc = n0 + r + i * 8;
    int ro = (z == 0) ? cc : 384 + ((cc >> 4) << 5) + ((z - 1) << 4) + (cc & 15);
    wsout[(size_t)ro * E_ + k0 + c] = __float2bfloat16(t[c][r + i * 8]);
  }
}

// ---------------------------------------------------------------------------
// Fused projection GEMM, BK=64 (proven 48.6us): [MT x 768] @ Ws^T ->
// q (rmsnormed) + keys (pooled+rmsnormed). 128x128 tile, 4 waves in M.
// ---------------------------------------------------------------------------
__global__ __launch_bounds__(256, 3) void gemm_qkg_mfma(
    const bf16* __restrict__ X, const bf16* __restrict__ Ws,
    const float* __restrict__ ape, bf16* __restrict__ Q,
    bf16* __restrict__ keys)
{
  __shared__ bf16 lds[2][8192];   // [128 rows][64 k] per buf = 16KB
  const int tid = threadIdx.x;
  const int lane = tid & 63, wv = tid >> 6;
  const int ll = lane & 15, lh = lane >> 4;
  const int m0 = blockIdx.x * 128, n0 = blockIdx.y * 128;
  const int srow = tid >> 3;
  const int sslot = (((tid & 7) ^ ((tid >> 3) & 7)) << 3);
  const bf16* pS = Ws + (size_t)(n0 + srow) * E_ + sslot;
  const bf16* pA0 = X + (size_t)(m0 + wv * 32 + ll) * E_ + lh * 8;
  const bf16* pA1 = pA0 + (size_t)16 * E_;

#define STAGE(b, k0) do { \
    char* base_ = (char*)&lds[b][0] + tid * 16; \
    GLD16(pS + (k0),            base_); \
    GLD16(pS + 32 * E_ + (k0),  base_ + 4096); \
    GLD16(pS + 64 * E_ + (k0),  base_ + 8192); \
    GLD16(pS + 96 * E_ + (k0),  base_ + 12288); \
  } while (0)
#define LOAD_A(dst, k0) do { \
    dst[0][0] = *reinterpret_cast<const short8*>(pA0 + (k0)); \
    dst[0][1] = *reinterpret_cast<const short8*>(pA0 + (k0) + 32); \
    dst[1][0] = *reinterpret_cast<const short8*>(pA1 + (k0)); \
    dst[1][1] = *reinterpret_cast<const short8*>(pA1 + (k0) + 32); \
  } while (0)

  f32x4 acc[2][8];
#pragma unroll
  for (int m = 0; m < 2; ++m)
#pragma unroll
    for (int n = 0; n < 8; ++n) acc[m][n] = (f32x4){0.f, 0.f, 0.f, 0.f};

  short8 curA[2][2], nxtA[2][2];   // [m][ks]
  LOAD_A(curA, 0);
  STAGE(0, 0);
#pragma unroll
  for (int m = 0; m < 2; ++m)
#pragma unroll
    for (int s = 0; s < 2; ++s) nxtA[m][s] = curA[m][s];

#pragma unroll
  for (int k = 0; k < 12; ++k) {
    const int k0 = k * 64;
    if (k < 11) {
      LOAD_A(nxtA, k0 + 64);
      STAGE((k + 1) & 1, k0 + 64);
    }
    if (k < 11) asm volatile("s_waitcnt vmcnt(8)" ::: "memory");
    else        asm volatile("s_waitcnt vmcnt(0)" ::: "memory");
    __builtin_amdgcn_s_barrier();
    __builtin_amdgcn_sched_barrier(0);
    const bf16* Lb = &lds[k & 1][0];
    short8 b0[8];
#pragma unroll
    for (int n = 0; n < 8; ++n)
      b0[n] = *reinterpret_cast<const short8*>(
          &Lb[(n * 16 + ll) * 64 + ((lh ^ (ll & 7)) << 3)]);
    asm volatile("s_waitcnt lgkmcnt(0)" ::: "memory");
    __builtin_amdgcn_sched_barrier(0);
#pragma unroll
    for (int m = 0; m < 2; ++m)
#pragma unroll
      for (int n = 0; n < 8; ++n)
        acc[m][n] = __builtin_amdgcn_mfma_f32_16x16x32_bf16(curA[m][0], b0[n], acc[m][n], 0, 0, 0);
    short8 b1[8];
#pragma unroll
    for (int n = 0; n < 8; ++n)
      b1[n] = *reinterpret_cast<const short8*>(
          &Lb[(n * 16 + ll) * 64 + (((4 + lh) ^ (ll & 7)) << 3)]);
    asm volatile("s_waitcnt lgkmcnt(0)" ::: "memory");
    __builtin_amdgcn_sched_barrier(0);
    __builtin_amdgcn_s_barrier();
#pragma unroll
    for (int m = 0; m < 2; ++m)
#pragma unroll
      for (int n = 0; n < 8; ++n)
        acc[m][n] = __builtin_amdgcn_mfma_f32_16x16x32_bf16(curA[m][1], b1[n], acc[m][n], 0, 0, 0);
#pragma unroll
    for (int m = 0; m < 2; ++m)
#pragma unroll
      for (int s = 0; s < 2; ++s) curA[m][s] = nxtA[m][s];
  }
#undef STAGE
#undef LOAD_A

  if (blockIdx.y < 3) {
#pragma unroll
    for (int m = 0; m < 2; ++m)
#pragma unroll
      for (int j = 0; j < 4; ++j) {
        int row = m0 + wv * 32 + m * 16 + lh * 4 + j;
#pragma unroll
        for (int h = 0; h < 2; ++h) {
          float ss = 0.f;
#pragma unroll
          for (int n = 4 * h; n < 4 * h + 4; ++n) ss += acc[m][n][j] * acc[m][n][j];
          ss += __shfl_xor(ss, 1, 64); ss += __shfl_xor(ss, 2, 64);
          ss += __shfl_xor(ss, 4, 64); ss += __shfl_xor(ss, 8, 64);
          float scl = rsqrtf(ss * (1.0f / D_) + 1e-6f);
#pragma unroll
          for (int n = 4 * h; n < 4 * h + 4; ++n)
            Q[(size_t)row * HD_ + n0 + n * 16 + ll] =
                __float2bfloat16(acc[m][n][j] * scl);
        }
      }
  } else {
    const int hcb = (n0 - 384) >> 1;
    float apev[4][4];
#pragma unroll
    for (int p = 0; p < 4; ++p) {
      int hc = hcb + p * 16 + ll;
#pragma unroll
      for (int j = 0; j < 4; ++j) apev[p][j] = ape[j * HD_ + hc];
    }
#pragma unroll
    for (int m = 0; m < 2; ++m) {
      float pooled[4];
#pragma unroll
      for (int p = 0; p < 4; ++p) {
        float g0 = acc[m][2 * p + 1][0] + apev[p][0];
        float g1 = acc[m][2 * p + 1][1] + apev[p][1];
        float g2 = acc[m][2 * p + 1][2] + apev[p][2];
        float g3 = acc[m][2 * p + 1][3] + apev[p][3];
        float mx = fmaxf(fmaxf(g0, g1), fmaxf(g2, g3));
        float e0 = expf(g0 - mx), e1 = expf(g1 - mx);
        float e2 = expf(g2 - mx), e3 = expf(g3 - mx);
        float inv = 1.0f / (e0 + e1 + e2 + e3);
        pooled[p] = (acc[m][2 * p][0] * e0 + acc[m][2 * p][1] * e1 +
                     acc[m][2 * p][2] * e2 + acc[m][2 * p][3] * e3) * inv;
      }
      float ss = pooled[0] * pooled[0] + pooled[1] * pooled[1] +
                 pooled[2] * pooled[2] + pooled[3] * pooled[3];
      ss += __shfl_xor(ss, 1, 64); ss += __shfl_xor(ss, 2, 64);
      ss += __shfl_xor(ss, 4, 64); ss += __shfl_xor(ss, 8, 64);
      float scl = rsqrtf(ss * (1.0f / D_) + 1e-6f);
      int prow = (m0 >> 2) + wv * 8 + m * 4 + lh;
#pragma unroll
      for (int p = 0; p < 4; ++p)
        keys[(size_t)prow * HD_ + hcb + p * 16 + ll] =
            __float2bfloat16(pooled[p] * scl);
    }
  }
}

#define CEx(a, bb) { unsigned h_ = umax_(a, bb), l_ = umin_(a, bb); a = h_; bb = l_; }
#define MERGE4() \
  _Pragma("unroll") \
  for (int st = 0; st < 2; ++st) { \
    const int off = 16 << st; \
    unsigned p0 = (unsigned)__shfl_xor((int)v0, off, 64); \
    unsigned p1 = (unsigned)__shfl_xor((int)v1, off, 64); \
    unsigned p2 = (unsigned)__shfl_xor((int)v2, off, 64); \
    unsigned p3 = (unsigned)__shfl_xor((int)v3, off, 64); \
    unsigned p4 = (unsigned)__shfl_xor((int)v4, off, 64); \
    unsigned p5 = (unsigned)__shfl_xor((int)v5, off, 64); \
    unsigned p6 = (unsigned)__shfl_xor((int)v6, off, 64); \
    unsigned p7 = (unsigned)__shfl_xor((int)v7, off, 64); \
    unsigned w0 = umax_(v0, p7), w1 = umax_(v1, p6); \
    unsigned w2 = umax_(v2, p5), w3 = umax_(v3, p4); \
    unsigned w4 = umax_(v4, p3), w5 = umax_(v5, p2); \
    unsigned w6 = umax_(v6, p1), w7 = umax_(v7, p0); \
    CEx(w0, w4); CEx(w1, w5); CEx(w2, w6); CEx(w3, w7); \
    CEx(w0, w2); CEx(w1, w3); CEx(w4, w6); CEx(w5, w7); \
    CEx(w0, w1); CEx(w2, w3); CEx(w4, w5); CEx(w6, w7); \
    v0 = w0; v1 = w1; v2 = w2; v3 = w3; v4 = w4; v5 = w5; v6 = w6; v7 = w7; \
  }

// ---------------------------------------------------------------------------
// Score + top-8 + in-kernel mask write (R19/R22-proven, byte-identical).
// Block = 32 t-rows (2 waves x 16), grid (128, B). Keys LDS-shared via
// coalesced global_load_lds, double-buffered, counted vmcnt.
// ---------------------------------------------------------------------------
__global__ __launch_bounds__(128, 2) void score_topk8(
    const bf16* __restrict__ Qall, const bf16* __restrict__ Kall,
    int* __restrict__ mask, int* __restrict__ ends)
{
  __shared__ bf16 kbuf[2][12288];   // [32 rows][48 slots of 16B], swizzled
  const int x = blockIdx.x;         // 0..127
  const int b = blockIdx.y;
  const int s = (b < 2) ? x : 127 - x;   // complementary balance pairing
  const int R0 = s << 5;                 // 32 rows per block
  const int tid = threadIdx.x;
  const int w = tid >> 6;                // wave 0..1
  const int lane = tid & 63;
  const int ll = lane & 15, lh = lane >> 4;

  if (x == 0 && b == 0) {                // group_ends (once)
    int g = tid;
#pragma unroll
    for (int c = 0; c < 8; ++c, g += 128) {
      int e = (g << 2) + 3;
      ends[g] = e < T_ - 1 ? e : T_ - 1;
    }
  }

  // zero-fill this block's 32 mask rows (128KB); oldest vmcnt-queue entries,
  // retired by the first counted vmcnt along with S(0).
  int* mbase = mask + ((size_t)b * T_ + R0) * G_;
  {
    int4* m4 = reinterpret_cast<int4*>(mbase);
    const int4 z = make_int4(0, 0, 0, 0);
#pragma unroll
    for (int i = 0; i < 64; ++i) m4[i * 128 + tid] = z;
  }

  const bf16* Qb = Qall + (size_t)b * T_ * HD_;
  const bf16* Kb = Kall + (size_t)b * G_ * HD_;
  const int t = R0 + 16 * w + ll;        // this lane's row
  const int gmax = (t + 1) >> 2;
  const int ntw = ((((R0 + 16 * w) >> 2) + 4) + 31) >> 5;  // wave's tiles
  const int nt  = ((((R0 + 16) >> 2) + 4) + 31) >> 5;      // block tiles

  // per-thread staging: chunk c=(12w+i): lane covers 16B unit u=c*64+lane
  // -> row r=u/48, phys slot sp=u%48, logical sl=sp^(r&7).
  const bf16* ksrc[12];
  int sdst[12];
#pragma unroll
  for (int i = 0; i < 12; ++i) {
    int u = (12 * w + i) * 64 + lane;
    int r = u / 48, sp = u - r * 48;
    int sl = sp ^ (r & 7);
    ksrc[i] = Kb + (size_t)r * HD_ + sl * 8;
    sdst[i] = u * 16;
  }
  // q frags (12 x 16B, once per kernel)
  short8 qf[12];
  {
    const bf16* pQ = Qb + (size_t)t * HD_ + lh * 8;
#pragma unroll
    for (int k = 0; k < 12; ++k)
      qf[k] = *reinterpret_cast<const short8*>(pQ + k * 32);
  }

#define KSTAGE(bf, g0) do { \
    char* bb_ = (char*)&kbuf[bf][0]; \
    _Pragma("unroll") \
    for (int i = 0; i < 12; ++i) \
      GLD16(ksrc[i] + (size_t)(g0) * HD_, bb_ + sdst[i]); \
  } while (0)

  unsigned v0 = 0, v1 = 0, v2 = 0, v3 = 0, v4 = 0, v5 = 0, v6 = 0, v7 = 0;
#define INS(xx) do { unsigned k_ = (xx), t_; \
    t_ = umax_(v0, k_); k_ = umin_(v0, k_); v0 = t_; \
    t_ = umax_(v1, k_); k_ = umin_(v1, k_); v1 = t_; \
    t_ = umax_(v2, k_); k_ = umin_(v2, k_); v2 = t_; \
    t_ = umax_(v3, k_); k_ = umin_(v3, k_); v3 = t_; \
    t_ = umax_(v4, k_); k_ = umin_(v4, k_); v4 = t_; \
    t_ = umax_(v5, k_); k_ = umin_(v5, k_); v5 = t_; \
    t_ = umax_(v6, k_); k_ = umin_(v6, k_); v6 = t_; \
    t_ = umax_(v7, k_); k_ = umin_(v7, k_); v7 = t_; } while (0)

  KSTAGE(0, 0);
  for (int mg = 0; mg < nt; ++mg) {
    if (mg + 1 < nt) {
      KSTAGE((mg + 1) & 1, (mg + 1) * 32);
      asm volatile("s_waitcnt vmcnt(12)" ::: "memory");
    } else {
      asm volatile("s_waitcnt vmcnt(0)" ::: "memory");
    }
    __builtin_amdgcn_s_barrier();          // buf[mg&1] staged by both waves
    __builtin_amdgcn_sched_barrier(0);
    if (mg < ntw) {                        // wave-uniform predicate
      const char* Lb = (const char*)&kbuf[mg & 1][0];
      f32x4 acc0 = (f32x4){0.f, 0.f, 0.f, 0.f};
      f32x4 acc1 = (f32x4){0.f, 0.f, 0.f, 0.f};
#pragma unroll
      for (int kk = 0; kk < 12; ++kk) {
        int sl = 4 * kk + lh;
        short8 k0 = *reinterpret_cast<const short8*>(
            Lb + (size_t)ll * 768 + ((sl ^ (ll & 7)) << 4));
        short8 k1 = *reinterpret_cast<const short8*>(
            Lb + (size_t)(16 + ll) * 768 + ((sl ^ (ll & 7)) << 4));
        acc0 = __builtin_amdgcn_mfma_f32_16x16x32_bf16(k0, qf[kk], acc0, 0, 0, 0);
        acc1 = __builtin_amdgcn_mfma_f32_16x16x32_bf16(k1, qf[kk], acc1, 0, 0, 0);
      }
      const int g0 = mg * 32;
      // |dot| < 384 (rmsnorm'd operands) -> dot+512 > 0: u32-order-isomorphic
#pragma unroll
      for (int j = 0; j < 4; ++j) {
        int g = g0 + lh * 4 + j;
        float xv = acc0[j] + 512.0f;
        unsigned key = (g < gmax)
            ? ((__builtin_bit_cast(unsigned, xv) & 0xFFFFFC00u) |
               (unsigned)(1023 - g))
            : 0u;
        INS(key);
      }
#pragma unroll
      for (int j = 0; j < 4; ++j) {
        int g = g0 + 16 + lh * 4 + j;
        float xv = acc1[j] + 512.0f;
        unsigned key = (g < gmax)
            ? ((__builtin_bit_cast(unsigned, xv) & 0xFFFFFC00u) |
               (unsigned)(1023 - g))
            : 0u;
        INS(key);
      }
    }
    __builtin_amdgcn_s_barrier();          // reads of buf[mg&1] done
  }
#undef INS
#undef KSTAGE

  MERGE4();                                // merge 4 lh-lanes -> final top-8

  __syncthreads();                         // cross-wave zero-fill ordering
  if (lh == 0) {                           // lane ll scatters its row
    int* rb = mbase + (size_t)(16 * w + ll) * G_;
    if (v0) rb[1023 - (v0 & 1023)] = 1;
    if (v1) rb[1023 - (v1 & 1023)] = 1;
    if (v2) rb[1023 - (v2 & 1023)] = 1;
    if (v3) rb[1023 - (v3 & 1023)] = 1;
    if (v4) rb[1023 - (v4 & 1023)] = 1;
    if (v5) rb[1023 - (v5 & 1023)] = 1;
    if (v6) rb[1023 - (v6 & 1023)] = 1;
    if (v7) rb[1023 - (v7 & 1023)] = 1;
  }
}

extern "C" void kernel_launch(void* const* d_in, const int* in_sizes, int n_in,
                              void* d_out, int out_size, void* d_ws, size_t ws_size,
                              hipStream_t stream)
{
  const float* x   = (const float*)d_in[0];
  const float* wq  = (const float*)d_in[1];
  const float* wk  = (const float*)d_in[2];
  const float* wg  = (const float*)d_in[3];
  const float* ape = (const float*)d_in[4];

  // ws: Ws[1152][768] bf16 | q[16384][384] bf16 | keys[4096][384] bf16
  bf16* Ws   = (bf16*)d_ws;
  bf16* qb   = Ws + (size_t)NS_ * E_;
  bf16* keys = qb + (size_t)MT_ * HD_;

  // x_bf16 staged in d_out (dead before the mask write overwrites it)
  bf16* xb = (bf16*)d_out;

  cvt_fused<<<dim3(6144 + 864), dim3(256), 0, stream>>>(x, wq, wk, wg, xb, Ws);

  gemm_qkg_mfma<<<dim3(MT_ / 128, NS_ / 128), dim3(256), 0, stream>>>(
      xb, Ws, ape, qb, keys);

  score_topk8<<<dim3(128, B_), dim3(128), 0, stream>>>(
      qb, keys, (int*)d_out, (int*)d_out + (size_t)B_ * T_ * G_);
}

// Round 25
// 100.512 us; speedup vs baseline: 1.0594x; 1.0327x over previous
//
#include <hip/hip_runtime.h>
#include <hip/hip_bf16.h>
#include <math.h>

#define B_    4
#define T_    4096
#define E_    768
#define H_    6
#define D_    64
#define HD_   384
#define G_    1024
#define RATIO_ 4
#define TOPK_ 8
#define MT_   (B_*T_)   // 16384 rows total
#define NS_   1152      // stacked N: [384 q][768 kg-interleaved]

typedef __attribute__((ext_vector_type(8))) short short8;
typedef __attribute__((ext_vector_type(4))) float f32x4;
typedef __hip_bfloat16 bf16;

#define GLD16(g, l) __builtin_amdgcn_global_load_lds( \
    (const __attribute__((address_space(1))) void*)(g), \
    (__attribute__((address_space(3))) void*)(l), 16, 0, 0)

static __device__ __forceinline__ unsigned short f2bf(float f) {
  bf16 h = __float2bfloat16(f);
  return __builtin_bit_cast(unsigned short, h);
}
static __device__ __forceinline__ unsigned umax_(unsigned a, unsigned b) { return a > b ? a : b; }
static __device__ __forceinline__ unsigned umin_(unsigned a, unsigned b) { return a > b ? b : a; }

// ---------------------------------------------------------------------------
// FUSED conversions: blocks [0,6144) convert x f32->bf16 (8 elems/thread);
// blocks [6144,7008) transpose+convert+stack weights into Ws [1152][768].
// ---------------------------------------------------------------------------
__global__ __launch_bounds__(256) void cvt_fused(
    const float* __restrict__ xin, const float* __restrict__ wq,
    const float* __restrict__ wk, const float* __restrict__ wg,
    bf16* __restrict__ xout, bf16* __restrict__ wsout)
{
  __shared__ float t[32][33];
  const int bid = blockIdx.x;
  if (bid < 6144) {
    size_t i = (size_t)bid * 256 + threadIdx.x;
    const float4* p = reinterpret_cast<const float4*>(xin) + i * 2;
    float4 v0 = p[0], v1 = p[1];
    float f[8] = {v0.x, v0.y, v0.z, v0.w, v1.x, v1.y, v1.z, v1.w};
    union { unsigned short u[8]; short8 v; } r;
#pragma unroll
    for (int k = 0; k < 8; ++k) r.u[k] = f2bf(f[k]);
    *reinterpret_cast<short8*>(xout + i * 8) = r.v;
    return;
  }
  const int wb = bid - 6144;          // 0..863
  const int z = wb / 288;             // 0..2
  const int rr = wb - z * 288;
  const int bx = rr % 24, by = rr / 24;
  const float* src = z == 0 ? wq : (z == 1 ? wk : wg);
  int r = threadIdx.x >> 5, c = threadIdx.x & 31;
  int k0 = bx * 32, n0 = by * 32;
#pragma unroll
  for (int i = 0; i < 4; ++i)
    t[r + i * 8][c] = src[(size_t)(k0 + r + i * 8) * HD_ + n0 + c];
  __syncthreads();
#pragma unroll
  for (int i = 0; i < 4; ++i) {
    int cc = n0 + r + i * 8;
    int ro = (z == 0) ? cc : 384 + ((cc >> 4) << 5) + ((z - 1) << 4) + (cc & 15);
    wsout[(size_t)ro * E_ + k0 + c] = __float2bfloat16(t[c][r + i * 8]);
  }
}

// ---------------------------------------------------------------------------
// Fused projection GEMM, BK=64 (proven 48.6us): [MT x 768] @ Ws^T ->
// q (rmsnormed) + keys (pooled+rmsnormed). 128x128 tile, 4 waves in M.
// ---------------------------------------------------------------------------
__global__ __launch_bounds__(256, 3) void gemm_qkg_mfma(
    const bf16* __restrict__ X, const bf16* __restrict__ Ws,
    const float* __restrict__ ape, bf16* __restrict__ Q,
    bf16* __restrict__ keys)
{
  __shared__ bf16 lds[2][8192];   // [128 rows][64 k] per buf = 16KB
  const int tid = threadIdx.x;
  const int lane = tid & 63, wv = tid >> 6;
  const int ll = lane & 15, lh = lane >> 4;
  const int m0 = blockIdx.x * 128, n0 = blockIdx.y * 128;
  const int srow = tid >> 3;
  const int sslot = (((tid & 7) ^ ((tid >> 3) & 7)) << 3);
  const bf16* pS = Ws + (size_t)(n0 + srow) * E_ + sslot;
  const bf16* pA0 = X + (size_t)(m0 + wv * 32 + ll) * E_ + lh * 8;
  const bf16* pA1 = pA0 + (size_t)16 * E_;

#define STAGE(b, k0) do { \
    char* base_ = (char*)&lds[b][0] + tid * 16; \
    GLD16(pS + (k0),            base_); \
    GLD16(pS + 32 * E_ + (k0),  base_ + 4096); \
    GLD16(pS + 64 * E_ + (k0),  base_ + 8192); \
    GLD16(pS + 96 * E_ + (k0),  base_ + 12288); \
  } while (0)
#define LOAD_A(dst, k0) do { \
    dst[0][0] = *reinterpret_cast<const short8*>(pA0 + (k0)); \
    dst[0][1] = *reinterpret_cast<const short8*>(pA0 + (k0) + 32); \
    dst[1][0] = *reinterpret_cast<const short8*>(pA1 + (k0)); \
    dst[1][1] = *reinterpret_cast<const short8*>(pA1 + (k0) + 32); \
  } while (0)

  f32x4 acc[2][8];
#pragma unroll
  for (int m = 0; m < 2; ++m)
#pragma unroll
    for (int n = 0; n < 8; ++n) acc[m][n] = (f32x4){0.f, 0.f, 0.f, 0.f};

  short8 curA[2][2], nxtA[2][2];   // [m][ks]
  LOAD_A(curA, 0);
  STAGE(0, 0);
#pragma unroll
  for (int m = 0; m < 2; ++m)
#pragma unroll
    for (int s = 0; s < 2; ++s) nxtA[m][s] = curA[m][s];

#pragma unroll
  for (int k = 0; k < 12; ++k) {
    const int k0 = k * 64;
    if (k < 11) {
      LOAD_A(nxtA, k0 + 64);
      STAGE((k + 1) & 1, k0 + 64);
    }
    if (k < 11) asm volatile("s_waitcnt vmcnt(8)" ::: "memory");
    else        asm volatile("s_waitcnt vmcnt(0)" ::: "memory");
    __builtin_amdgcn_s_barrier();
    __builtin_amdgcn_sched_barrier(0);
    const bf16* Lb = &lds[k & 1][0];
    short8 b0[8];
#pragma unroll
    for (int n = 0; n < 8; ++n)
      b0[n] = *reinterpret_cast<const short8*>(
          &Lb[(n * 16 + ll) * 64 + ((lh ^ (ll & 7)) << 3)]);
    asm volatile("s_waitcnt lgkmcnt(0)" ::: "memory");
    __builtin_amdgcn_sched_barrier(0);
#pragma unroll
    for (int m = 0; m < 2; ++m)
#pragma unroll
      for (int n = 0; n < 8; ++n)
        acc[m][n] = __builtin_amdgcn_mfma_f32_16x16x32_bf16(curA[m][0], b0[n], acc[m][n], 0, 0, 0);
    short8 b1[8];
#pragma unroll
    for (int n = 0; n < 8; ++n)
      b1[n] = *reinterpret_cast<const short8*>(
          &Lb[(n * 16 + ll) * 64 + (((4 + lh) ^ (ll & 7)) << 3)]);
    asm volatile("s_waitcnt lgkmcnt(0)" ::: "memory");
    __builtin_amdgcn_sched_barrier(0);
    __builtin_amdgcn_s_barrier();
#pragma unroll
    for (int m = 0; m < 2; ++m)
#pragma unroll
      for (int n = 0; n < 8; ++n)
        acc[m][n] = __builtin_amdgcn_mfma_f32_16x16x32_bf16(curA[m][1], b1[n], acc[m][n], 0, 0, 0);
#pragma unroll
    for (int m = 0; m < 2; ++m)
#pragma unroll
      for (int s = 0; s < 2; ++s) curA[m][s] = nxtA[m][s];
  }
#undef STAGE
#undef LOAD_A

  if (blockIdx.y < 3) {
#pragma unroll
    for (int m = 0; m < 2; ++m)
#pragma unroll
      for (int j = 0; j < 4; ++j) {
        int row = m0 + wv * 32 + m * 16 + lh * 4 + j;
#pragma unroll
        for (int h = 0; h < 2; ++h) {
          float ss = 0.f;
#pragma unroll
          for (int n = 4 * h; n < 4 * h + 4; ++n) ss += acc[m][n][j] * acc[m][n][j];
          ss += __shfl_xor(ss, 1, 64); ss += __shfl_xor(ss, 2, 64);
          ss += __shfl_xor(ss, 4, 64); ss += __shfl_xor(ss, 8, 64);
          float scl = rsqrtf(ss * (1.0f / D_) + 1e-6f);
#pragma unroll
          for (int n = 4 * h; n < 4 * h + 4; ++n)
            Q[(size_t)row * HD_ + n0 + n * 16 + ll] =
                __float2bfloat16(acc[m][n][j] * scl);
        }
      }
  } else {
    const int hcb = (n0 - 384) >> 1;
    float apev[4][4];
#pragma unroll
    for (int p = 0; p < 4; ++p) {
      int hc = hcb + p * 16 + ll;
#pragma unroll
      for (int j = 0; j < 4; ++j) apev[p][j] = ape[j * HD_ + hc];
    }
#pragma unroll
    for (int m = 0; m < 2; ++m) {
      float pooled[4];
#pragma unroll
      for (int p = 0; p < 4; ++p) {
        float g0 = acc[m][2 * p + 1][0] + apev[p][0];
        float g1 = acc[m][2 * p + 1][1] + apev[p][1];
        float g2 = acc[m][2 * p + 1][2] + apev[p][2];
        float g3 = acc[m][2 * p + 1][3] + apev[p][3];
        float mx = fmaxf(fmaxf(g0, g1), fmaxf(g2, g3));
        float e0 = expf(g0 - mx), e1 = expf(g1 - mx);
        float e2 = expf(g2 - mx), e3 = expf(g3 - mx);
        float inv = 1.0f / (e0 + e1 + e2 + e3);
        pooled[p] = (acc[m][2 * p][0] * e0 + acc[m][2 * p][1] * e1 +
                     acc[m][2 * p][2] * e2 + acc[m][2 * p][3] * e3) * inv;
      }
      float ss = pooled[0] * pooled[0] + pooled[1] * pooled[1] +
                 pooled[2] * pooled[2] + pooled[3] * pooled[3];
      ss += __shfl_xor(ss, 1, 64); ss += __shfl_xor(ss, 2, 64);
      ss += __shfl_xor(ss, 4, 64); ss += __shfl_xor(ss, 8, 64);
      float scl = rsqrtf(ss * (1.0f / D_) + 1e-6f);
      int prow = (m0 >> 2) + wv * 8 + m * 4 + lh;
#pragma unroll
      for (int p = 0; p < 4; ++p)
        keys[(size_t)prow * HD_ + hcb + p * 16 + ll] =
            __float2bfloat16(pooled[p] * scl);
    }
  }
}

#define CEx(a, bb) { unsigned h_ = umax_(a, bb), l_ = umin_(a, bb); a = h_; bb = l_; }
#define MERGE4() \
  _Pragma("unroll") \
  for (int st = 0; st < 2; ++st) { \
    const int off = 16 << st; \
    unsigned p0 = (unsigned)__shfl_xor((int)v0, off, 64); \
    unsigned p1 = (unsigned)__shfl_xor((int)v1, off, 64); \
    unsigned p2 = (unsigned)__shfl_xor((int)v2, off, 64); \
    unsigned p3 = (unsigned)__shfl_xor((int)v3, off, 64); \
    unsigned p4 = (unsigned)__shfl_xor((int)v4, off, 64); \
    unsigned p5 = (unsigned)__shfl_xor((int)v5, off, 64); \
    unsigned p6 = (unsigned)__shfl_xor((int)v6, off, 64); \
    unsigned p7 = (unsigned)__shfl_xor((int)v7, off, 64); \
    unsigned w0 = umax_(v0, p7), w1 = umax_(v1, p6); \
    unsigned w2 = umax_(v2, p5), w3 = umax_(v3, p4); \
    unsigned w4 = umax_(v4, p3), w5 = umax_(v5, p2); \
    unsigned w6 = umax_(v6, p1), w7 = umax_(v7, p0); \
    CEx(w0, w4); CEx(w1, w5); CEx(w2, w6); CEx(w3, w7); \
    CEx(w0, w2); CEx(w1, w3); CEx(w4, w6); CEx(w5, w7); \
    CEx(w0, w1); CEx(w2, w3); CEx(w4, w5); CEx(w6, w7); \
    v0 = w0; v1 = w1; v2 = w2; v3 = w3; v4 = w4; v5 = w5; v6 = w6; v7 = w7; \
  }

// ---------------------------------------------------------------------------
// Score + top-8 + in-kernel mask write. R22 structure + INTERLEAVED zero-fill:
// 6 int4 stores per tile iteration (wrapping mod 64; redundant zeros are
// harmless), issued before that iter's KSTAGE. Stores share vmcnt with loads
// on CDNA, so the steady wait becomes vmcnt(18):
//   queue [st6(mg-1), S(mg)12] + issue [st6(mg), S(mg+1)12] = 36
//   vmcnt(18) drains st6(mg-1)+S(mg), leaves [st6(mg), S(mg+1)] = 18.
// This moves the 128KB zero-fill drain off the kernel-start critical path.
// ---------------------------------------------------------------------------
__global__ __launch_bounds__(128, 2) void score_topk8(
    const bf16* __restrict__ Qall, const bf16* __restrict__ Kall,
    int* __restrict__ mask, int* __restrict__ ends)
{
  __shared__ bf16 kbuf[2][12288];   // [32 rows][48 slots of 16B], swizzled
  const int x = blockIdx.x;         // 0..127
  const int b = blockIdx.y;
  const int s = (b < 2) ? x : 127 - x;   // complementary balance pairing
  const int R0 = s << 5;                 // 32 rows per block
  const int tid = threadIdx.x;
  const int w = tid >> 6;                // wave 0..1
  const int lane = tid & 63;
  const int ll = lane & 15, lh = lane >> 4;

  if (x == 0 && b == 0) {                // group_ends (once)
    int g = tid;
#pragma unroll
    for (int c = 0; c < 8; ++c, g += 128) {
      int e = (g << 2) + 3;
      ends[g] = e < T_ - 1 ? e : T_ - 1;
    }
  }

  int* mbase = mask + ((size_t)b * T_ + R0) * G_;
  int4* m4 = reinterpret_cast<int4*>(mbase);
  const int4 zz = make_int4(0, 0, 0, 0);

  const bf16* Qb = Qall + (size_t)b * T_ * HD_;
  const bf16* Kb = Kall + (size_t)b * G_ * HD_;
  const int t = R0 + 16 * w + ll;        // this lane's row
  const int gmax = (t + 1) >> 2;
  const int ntw = ((((R0 + 16 * w) >> 2) + 4) + 31) >> 5;  // wave's tiles
  const int nt  = ((((R0 + 16) >> 2) + 4) + 31) >> 5;      // block tiles

  // per-thread staging: chunk c=(12w+i): lane covers 16B unit u=c*64+lane
  // -> row r=u/48, phys slot sp=u%48, logical sl=sp^(r&7).
  const bf16* ksrc[12];
  int sdst[12];
#pragma unroll
  for (int i = 0; i < 12; ++i) {
    int u = (12 * w + i) * 64 + lane;
    int r = u / 48, sp = u - r * 48;
    int sl = sp ^ (r & 7);
    ksrc[i] = Kb + (size_t)r * HD_ + sl * 8;
    sdst[i] = u * 16;
  }
  // q frags (12 x 16B, once per kernel)
  short8 qf[12];
  {
    const bf16* pQ = Qb + (size_t)t * HD_ + lh * 8;
#pragma unroll
    for (int k = 0; k < 12; ++k)
      qf[k] = *reinterpret_cast<const short8*>(pQ + k * 32);
  }

#define KSTAGE(bf, g0) do { \
    char* bb_ = (char*)&kbuf[bf][0]; \
    _Pragma("unroll") \
    for (int i = 0; i < 12; ++i) \
      GLD16(ksrc[i] + (size_t)(g0) * HD_, bb_ + sdst[i]); \
  } while (0)

  unsigned v0 = 0, v1 = 0, v2 = 0, v3 = 0, v4 = 0, v5 = 0, v6 = 0, v7 = 0;
#define INS(xx) do { unsigned k_ = (xx), t_; \
    t_ = umax_(v0, k_); k_ = umin_(v0, k_); v0 = t_; \
    t_ = umax_(v1, k_); k_ = umin_(v1, k_); v1 = t_; \
    t_ = umax_(v2, k_); k_ = umin_(v2, k_); v2 = t_; \
    t_ = umax_(v3, k_); k_ = umin_(v3, k_); v3 = t_; \
    t_ = umax_(v4, k_); k_ = umin_(v4, k_); v4 = t_; \
    t_ = umax_(v5, k_); k_ = umin_(v5, k_); v5 = t_; \
    t_ = umax_(v6, k_); k_ = umin_(v6, k_); v6 = t_; \
    t_ = umax_(v7, k_); k_ = umin_(v7, k_); v7 = t_; } while (0)

  KSTAGE(0, 0);
  int zdone = 0;
  for (int mg = 0; mg < nt; ++mg) {
    if (mg + 1 < nt) {
      // 6 zero-fill stores (wrap mod 64; redundant zeros harmless)
#pragma unroll
      for (int j = 0; j < 6; ++j)
        m4[(((mg * 6 + j) & 63) * 128) + tid] = zz;
      zdone = (mg + 1) * 6;
      KSTAGE((mg + 1) & 1, (mg + 1) * 32);
      asm volatile("s_waitcnt vmcnt(18)" ::: "memory");
    } else {
      asm volatile("s_waitcnt vmcnt(0)" ::: "memory");
    }
    __builtin_amdgcn_s_barrier();          // buf[mg&1] staged by both waves
    __builtin_amdgcn_sched_barrier(0);
    if (mg < ntw) {                        // wave-uniform predicate
      const char* Lb = (const char*)&kbuf[mg & 1][0];
      f32x4 acc0 = (f32x4){0.f, 0.f, 0.f, 0.f};
      f32x4 acc1 = (f32x4){0.f, 0.f, 0.f, 0.f};
#pragma unroll
      for (int kk = 0; kk < 12; ++kk) {
        int sl = 4 * kk + lh;
        short8 k0 = *reinterpret_cast<const short8*>(
            Lb + (size_t)ll * 768 + ((sl ^ (ll & 7)) << 4));
        short8 k1 = *reinterpret_cast<const short8*>(
            Lb + (size_t)(16 + ll) * 768 + ((sl ^ (ll & 7)) << 4));
        acc0 = __builtin_amdgcn_mfma_f32_16x16x32_bf16(k0, qf[kk], acc0, 0, 0, 0);
        acc1 = __builtin_amdgcn_mfma_f32_16x16x32_bf16(k1, qf[kk], acc1, 0, 0, 0);
      }
      const int g0 = mg * 32;
      // |dot| < 384 (rmsnorm'd operands) -> dot+512 > 0: u32-order-isomorphic
#pragma unroll
      for (int j = 0; j < 4; ++j) {
        int g = g0 + lh * 4 + j;
        float xv = acc0[j] + 512.0f;
        unsigned key = (g < gmax)
            ? ((__builtin_bit_cast(unsigned, xv) & 0xFFFFFC00u) |
               (unsigned)(1023 - g))
            : 0u;
        INS(key);
      }
#pragma unroll
      for (int j = 0; j < 4; ++j) {
        int g = g0 + 16 + lh * 4 + j;
        float xv = acc1[j] + 512.0f;
        unsigned key = (g < gmax)
            ? ((__builtin_bit_cast(unsigned, xv) & 0xFFFFFC00u) |
               (unsigned)(1023 - g))
            : 0u;
        INS(key);
      }
    }
    __builtin_amdgcn_s_barrier();          // reads of buf[mg&1] done
  }
#undef INS
#undef KSTAGE

  // finish zero-fill for shallow blocks
  for (int j = zdone; j < 64; ++j) m4[j * 128 + tid] = zz;
  asm volatile("s_waitcnt vmcnt(0)" ::: "memory");

  MERGE4();                                // merge 4 lh-lanes -> final top-8

  __syncthreads();                         // cross-wave zero-fill ordering
  if (lh == 0) {                           // lane ll scatters its row
    int* rb = mbase + (size_t)(16 * w + ll) * G_;
    if (v0) rb[1023 - (v0 & 1023)] = 1;
    if (v1) rb[1023 - (v1 & 1023)] = 1;
    if (v2) rb[1023 - (v2 & 1023)] = 1;
    if (v3) rb[1023 - (v3 & 1023)] = 1;
    if (v4) rb[1023 - (v4 & 1023)] = 1;
    if (v5) rb[1023 - (v5 & 1023)] = 1;
    if (v6) rb[1023 - (v6 & 1023)] = 1;
    if (v7) rb[1023 - (v7 & 1023)] = 1;
  }
}

extern "C" void kernel_launch(void* const* d_in, const int* in_sizes, int n_in,
                              void* d_out, int out_size, void* d_ws, size_t ws_size,
                              hipStream_t stream)
{
  const float* x   = (const float*)d_in[0];
  const float* wq  = (const float*)d_in[1];
  const float* wk  = (const float*)d_in[2];
  const float* wg  = (const float*)d_in[3];
  const float* ape = (const float*)d_in[4];

  // ws: Ws[1152][768] bf16 | q[16384][384] bf16 | keys[4096][384] bf16
  bf16* Ws   = (bf16*)d_ws;
  bf16* qb   = Ws + (size_t)NS_ * E_;
  bf16* keys = qb + (size_t)MT_ * HD_;

  // x_bf16 staged in d_out (dead before the mask write overwrites it)
  bf16* xb = (bf16*)d_out;

  cvt_fused<<<dim3(6144 + 864), dim3(256), 0, stream>>>(x, wq, wk, wg, xb, Ws);

  gemm_qkg_mfma<<<dim3(MT_ / 128, NS_ / 128), dim3(256), 0, stream>>>(
      xb, Ws, ape, qb, keys);

  score_topk8<<<dim3(128, B_), dim3(128), 0, stream>>>(
      qb, keys, (int*)d_out, (int*)d_out + (size_t)B_ * T_ * G_);
}